// Round 15
// baseline (4741.522 us; speedup 1.0000x reference)
//
#include <hip/hip_runtime.h>
#include <hip/hip_bf16.h>
#include <math.h>

// Problem constants (B=32, Ts=64, Tt=66, E=H=512, V=16000)
#define TSRC 64
#define TTRG 66
#define NVOC 15996   // V-4
#define NTILE 125    // ceil(15996/128)

__device__ __forceinline__ float sigm(float x){ return 1.f/(1.f+expf(-x)); }

// ---------------------------------------------------------------------------
// Input GEMM 128x128 tile, conflict-free dual-float4 fragments.
// ---------------------------------------------------------------------------
__global__ __launch_bounds__(256)
void k_gemm128(const float* __restrict__ A, int lda,
               const float* __restrict__ Bw, int ldb,
               const float* __restrict__ bias,
               float* __restrict__ C, int ldc, int K, int nNb)
{
  const int tid = threadIdx.x;
  const int mb = blockIdx.x / nNb;
  const int nb = blockIdx.x % nNb;
  const int m0 = mb*128, n0 = nb*128;

  __shared__ alignas(16) float As[16][132];
  __shared__ alignas(16) float Bs[16][132];
  const int tx = tid & 15;
  const int ty = tid >> 4;
  float acc[8][8];
  #pragma unroll
  for (int i=0;i<8;i++)
    #pragma unroll
    for (int j=0;j<8;j++) acc[i][j]=0.f;

  for (int kt=0; kt<K; kt+=16) {
    #pragma unroll
    for (int i=tid; i<128*16; i+=256) {
      int m = i>>4, k = i&15;
      As[k][m] = A[(size_t)(m0+m)*lda + kt + k];
    }
    #pragma unroll
    for (int i=tid; i<128*16; i+=256) {
      int n = i>>4, k = i&15;
      Bs[k][n] = Bw[(size_t)(n0+n)*ldb + kt + k];
    }
    __syncthreads();
    #pragma unroll
    for (int k=0;k<16;k++) {
      float4 a0 = *reinterpret_cast<const float4*>(&As[k][ty*4]);
      float4 a1 = *reinterpret_cast<const float4*>(&As[k][64+ty*4]);
      float4 b0 = *reinterpret_cast<const float4*>(&Bs[k][tx*4]);
      float4 b1 = *reinterpret_cast<const float4*>(&Bs[k][64+tx*4]);
      float av[8] = {a0.x,a0.y,a0.z,a0.w,a1.x,a1.y,a1.z,a1.w};
      float bv[8] = {b0.x,b0.y,b0.z,b0.w,b1.x,b1.y,b1.z,b1.w};
      #pragma unroll
      for (int i=0;i<8;i++)
        #pragma unroll
        for (int j=0;j<8;j++)
          acc[i][j] = fmaf(av[i], bv[j], acc[i][j]);
    }
    __syncthreads();
  }
  #pragma unroll
  for (int i=0;i<8;i++) {
    int m = m0 + ((i<4) ? ty*4+i : 64+ty*4+(i-4));
    int nA = n0 + tx*4, nB = n0 + 64 + tx*4;
    float4 v0, v1;
    v0.x = acc[i][0] + (bias?bias[nA+0]:0.f);
    v0.y = acc[i][1] + (bias?bias[nA+1]:0.f);
    v0.z = acc[i][2] + (bias?bias[nA+2]:0.f);
    v0.w = acc[i][3] + (bias?bias[nA+3]:0.f);
    v1.x = acc[i][4] + (bias?bias[nB+0]:0.f);
    v1.y = acc[i][5] + (bias?bias[nB+1]:0.f);
    v1.z = acc[i][6] + (bias?bias[nB+2]:0.f);
    v1.w = acc[i][7] + (bias?bias[nB+3]:0.f);
    *reinterpret_cast<float4*>(&C[(size_t)m*ldc + nA]) = v0;
    *reinterpret_cast<float4*>(&C[(size_t)m*ldc + nB]) = v1;
  }
}

// ---------------------------------------------------------------------------
// Fused logits GEMM + per-tile row reduction, conflict-free fragments.
// XCD-swizzled: all 16 row-blocks sharing a W2 tile land on one XCD.
// ---------------------------------------------------------------------------
__global__ __launch_bounds__(256)
void k_logits(const float* __restrict__ A, const float* __restrict__ Bw,
              const int* __restrict__ trg,
              float* __restrict__ Pmax, int* __restrict__ Parg,
              float* __restrict__ Psum, float* __restrict__ Ltgt)
{
  const int tid = threadIdx.x;
  const int j8   = blockIdx.x & 7;
  const int mb   = (blockIdx.x >> 3) & 15;
  const int nb   = ((blockIdx.x >> 7) << 3) + j8;
  if (nb >= NTILE) return;
  const int m0 = mb*128, n0 = nb*128;

  __shared__ alignas(16) float As[16][132];
  __shared__ alignas(16) float Bs[16][132];
  const int tx = tid & 15;
  const int ty = tid >> 4;
  float acc[8][8];
  #pragma unroll
  for (int i=0;i<8;i++)
    #pragma unroll
    for (int j=0;j<8;j++) acc[i][j]=0.f;

  for (int kt=0; kt<512; kt+=16) {
    #pragma unroll
    for (int i=tid; i<128*16; i+=256) {
      int m = i>>4, k = i&15;
      As[k][m] = A[(size_t)(m0+m)*512 + kt + k];
    }
    #pragma unroll
    for (int i=tid; i<128*16; i+=256) {
      int n = i>>4, k = i&15;
      int gn = n0+n;
      Bs[k][n] = (gn < NVOC) ? Bw[(size_t)gn*512 + kt + k] : 0.f;
    }
    __syncthreads();
    #pragma unroll
    for (int k=0;k<16;k++) {
      float4 a0 = *reinterpret_cast<const float4*>(&As[k][ty*4]);
      float4 a1 = *reinterpret_cast<const float4*>(&As[k][64+ty*4]);
      float4 b0 = *reinterpret_cast<const float4*>(&Bs[k][tx*4]);
      float4 b1 = *reinterpret_cast<const float4*>(&Bs[k][64+tx*4]);
      float av[8] = {a0.x,a0.y,a0.z,a0.w,a1.x,a1.y,a1.z,a1.w};
      float bv[8] = {b0.x,b0.y,b0.z,b0.w,b1.x,b1.y,b1.z,b1.w};
      #pragma unroll
      for (int i=0;i<8;i++)
        #pragma unroll
        for (int j=0;j<8;j++)
          acc[i][j] = fmaf(av[i], bv[j], acc[i][j]);
    }
    __syncthreads();
  }

  #pragma unroll
  for (int i=0;i<8;i++) {
    int r = m0 + ((i<4) ? ty*4+i : 64+ty*4+(i-4));   // row = step*32 + b
    int step = r >> 5, b = r & 31;
    int tgt = trg[b*TTRG + step + 1];
    int ti = tgt - 4;
    float m = -3.4e38f; int am = 0x7fffffff;
    #pragma unroll
    for (int j=0;j<8;j++) {
      int gn = n0 + ((j<4) ? tx*4+j : 64+tx*4+(j-4));
      if (gn < NVOC) {
        float x = acc[i][j];
        if (x > m || (x == m && gn < am)) { m = x; am = gn; }
      }
    }
    float s = 0.f;
    float lt = 0.f;
    #pragma unroll
    for (int j=0;j<8;j++) {
      int gn = n0 + ((j<4) ? tx*4+j : 64+tx*4+(j-4));
      if (gn < NVOC) {
        s += expf(acc[i][j] - m);
        if (gn == ti) lt = acc[i][j];
      }
    }
    #pragma unroll
    for (int d=1; d<16; d<<=1) {
      float m2 = __shfl_xor(m, d);
      int   a2 = __shfl_xor(am, d);
      float s2 = __shfl_xor(s, d);
      float l2 = __shfl_xor(lt, d);
      float M = fmaxf(m, m2);
      s = s*expf(m - M) + s2*expf(m2 - M);
      if (m2 > m || (m2 == m && a2 < am)) am = a2;
      m = M;
      lt += l2;
    }
    if (tx == 0) {
      size_t pi = (size_t)r*NTILE + nb;
      Pmax[pi] = m; Parg[pi] = am; Psum[pi] = s;
      if (ti >= n0 && ti < n0 + 128) Ltgt[r] = lt;
    }
  }
}

// ---------------------------------------------------------------------------
// Tiled GEMM (64x64, used for W1 only): C = A*B^T, tanh epilogue.
// ---------------------------------------------------------------------------
struct GArgs {
  const float* A;  int lda;
  const float* Bw; int ldb;
  const float* bias;
  float* C; int ldc;
  int N; int K; int nNb; int act;
};

template<int BM,int BN,int BK,int TM,int TN>
__global__ __launch_bounds__(256)
void k_gemm(GArgs a)
{
  const int tid = threadIdx.x;
  const int mb = blockIdx.x / a.nNb;
  const int nb = blockIdx.x % a.nNb;
  const int m0 = mb*BM, n0 = nb*BN;
  const float* A  = a.A + (size_t)m0*a.lda;
  const float* Bw = a.Bw;

  __shared__ float As[BK][BM+1];
  __shared__ float Bs[BK][BN+4];
  const int tx = tid % (BN/TN);
  const int ty = tid / (BN/TN);
  float acc[TM][TN];
  #pragma unroll
  for (int i=0;i<TM;i++)
    #pragma unroll
    for (int j=0;j<TN;j++) acc[i][j]=0.f;

  for (int kt=0; kt<a.K; kt+=BK) {
    #pragma unroll
    for (int i=tid; i<BM*BK; i+=256) {
      int m = i/BK, k = i%BK;
      As[k][m] = A[(size_t)m*a.lda + kt + k];
    }
    #pragma unroll
    for (int i=tid; i<BN*BK; i+=256) {
      int n = i/BK, k = i%BK;
      int gn = n0+n;
      Bs[k][n] = (gn < a.N) ? Bw[(size_t)gn*a.ldb + kt + k] : 0.f;
    }
    __syncthreads();
    #pragma unroll
    for (int k=0;k<BK;k++) {
      float av[TM], bv[TN];
      #pragma unroll
      for (int i=0;i<TM;i++) av[i]=As[k][ty*TM+i];
      #pragma unroll
      for (int j=0;j<TN;j++) bv[j]=Bs[k][tx*TN+j];
      #pragma unroll
      for (int i=0;i<TM;i++)
        #pragma unroll
        for (int j=0;j<TN;j++)
          acc[i][j] = fmaf(av[i], bv[j], acc[i][j]);
    }
    __syncthreads();
  }
  #pragma unroll
  for (int i=0;i<TM;i++) {
    int m = m0 + ty*TM + i;
    #pragma unroll
    for (int j=0;j<TN;j++) {
      int n = n0 + tx*TN + j;
      if (n < a.N) {
        float v = acc[i][j];
        if (a.bias) v += a.bias[n];
        if (a.act)  v = tanhf(v);
        a.C[(size_t)m*a.ldc + n] = v;
      }
    }
  }
}

// Combine per-tile partials -> nll + pred per row.
__global__ __launch_bounds__(128)
void k_combine(const float* __restrict__ Pmax, const int* __restrict__ Parg,
               const float* __restrict__ Psum, const float* __restrict__ Ltgt,
               const int* __restrict__ trg,
               float* __restrict__ nll, float* __restrict__ outp)
{
  int r = blockIdx.x;
  int step = r >> 5, b = r & 31;
  int tid = threadIdx.x;
  __shared__ float sm[128]; __shared__ int sa[128]; __shared__ float ssum[128];
  float m = -3.4e38f; int am = 0x7fffffff; float s = 0.f;
  if (tid < NTILE) {
    size_t pi = (size_t)r*NTILE + tid;
    m = Pmax[pi]; am = Parg[pi]; s = Psum[pi];
  }
  sm[tid]=m; sa[tid]=am; ssum[tid]=s; __syncthreads();
  for (int off=64; off; off>>=1) {
    if (tid < off) {
      float m2 = sm[tid+off]; int a2 = sa[tid+off]; float s2 = ssum[tid+off];
      float m1 = sm[tid];     int a1 = sa[tid];     float s1 = ssum[tid];
      float M = fmaxf(m1, m2);
      ssum[tid] = s1*expf(m1 - M) + s2*expf(m2 - M);
      if (m2 > m1 || (m2 == m1 && a2 < a1)) sa[tid] = a2;
      sm[tid] = M;
    }
    __syncthreads();
  }
  if (tid == 0) {
    int tgt = trg[b*TTRG + step + 1];
    float nl = 0.f;
    if (tgt != 0) nl = -(Ltgt[r] - sm[0] - logf(ssum[0]));
    nll[step*32 + b] = nl;
    outp[1 + b*64 + step] = (float)(sa[0] + 4);
  }
}

// Embedding gather
__global__ void k_gather(const float* __restrict__ emb, const int* __restrict__ tok,
                         float* __restrict__ outp, int Tfull)
{
  int r = blockIdx.x;
  int t = r >> 5, b = r & 31;
  int token = tok[b*Tfull + t];
  const float4* s = (const float4*)(emb + (size_t)token*512);
  float4* d = (float4*)(outp + (size_t)r*512);
  d[threadIdx.x] = s[threadIdx.x];
}

// ---------------------------------------------------------------------------
// FUSED encoder LSTM step (layer 0): full-K gates + update + scatter to x1.
// ---------------------------------------------------------------------------
__global__ __launch_bounds__(256)
void k_estep(const float* __restrict__ Whh,   // [2][2048][512]
             const float* __restrict__ xg,    // [2048][4096]
             const float* __restrict__ hin,   // [2*32][512]
             float* __restrict__ hout,        // [2*32][512]
             float* __restrict__ cst,         // [2*32][512]
             float* __restrict__ xout, int s)
{
  const int bid = blockIdx.x;
  const int dir = bid >> 7;
  const int j0  = (bid & 127) * 4;
  const int tid = threadIdx.x;
  const int kg  = tid >> 5;
  const int b   = tid & 31;
  __shared__ float4 wl4[16*128];
  __shared__ float red[4*16*33];

  {
    const float* W = Whh + (size_t)dir*2048*512;
    for (int idx = tid; idx < 16*128; idx += 256) {
      int r = idx >> 7, c = idx & 127;
      int g = r >> 2, jj = r & 3;
      wl4[idx] = ((const float4*)(W + (size_t)(g*512 + j0 + jj)*512))[c];
    }
  }
  float4 hreg[16];
  {
    const float4* H4 = (const float4*)(hin + (size_t)dir*32*512);
    #pragma unroll
    for (int j=0;j<16;j++) hreg[j] = H4[(size_t)b*128 + kg*16 + j];
  }
  __syncthreads();

  float acc[16];
  #pragma unroll
  for (int r=0;r<16;r++) {
    const float4* wr = wl4 + r*128 + kg*16;
    float a0=0.f,a1=0.f,a2=0.f,a3=0.f;
    #pragma unroll
    for (int j=0;j<16;j++) {
      float4 w = wr[j];
      a0 = fmaf(w.x, hreg[j].x, a0);
      a1 = fmaf(w.y, hreg[j].y, a1);
      a2 = fmaf(w.z, hreg[j].z, a2);
      a3 = fmaf(w.w, hreg[j].w, a3);
    }
    acc[r] = (a0+a1)+(a2+a3);
  }
  #pragma unroll
  for (int r=0;r<16;r++) acc[r] += __shfl_xor(acc[r], 32);
  const int wv = tid >> 6;
  if ((tid & 32) == 0) {
    #pragma unroll
    for (int r=0;r<16;r++) red[wv*528 + r*33 + b] = acc[r];
  }
  __syncthreads();

  if (tid < 128) {
    int jj = tid >> 5, bb = tid & 31;
    int jh = j0 + jj;
    int t  = dir ? (63 - s) : s;
    const float* x = xg + ((size_t)t*32 + bb)*4096 + dir*2048;
    float g4[4];
    #pragma unroll
    for (int g=0; g<4; g++) {
      int r = g*4 + jj;
      g4[g] = ((red[0*528 + r*33 + bb] + red[1*528 + r*33 + bb])
             + (red[2*528 + r*33 + bb] + red[3*528 + r*33 + bb]))
             + x[g*512 + jh];
    }
    size_t ci = ((size_t)dir*32 + bb)*512 + jh;
    float cn = sigm(g4[1])*cst[ci] + sigm(g4[0])*tanhf(g4[2]);
    float hn = sigm(g4[3])*tanhf(cn);
    cst[ci] = cn;
    hout[ci] = hn;
    xout[((size_t)t*32 + bb)*1024 + dir*512 + jh] = hn;   // x1
  }
}

// ---------------------------------------------------------------------------
// MERGED step: blocks 0-255 = encoder L1 step s (writes encout);
// blocks 256-511 = decoder step s (in-kernel Wih·x_t + Whh·h + bias -> Hall).
// The two chains are independent; sharing one launch halves serial dispatches.
// ---------------------------------------------------------------------------
__global__ __launch_bounds__(256)
void k_mstep(const float* __restrict__ eWhh,   // [2][2048][512]
             const float* __restrict__ xg,     // enc L1 input gates [2048][4096]
             const float* __restrict__ ehin, float* __restrict__ ehout,
             float* __restrict__ ecst,         // [2*32][512]
             float* __restrict__ encout,       // [32][64][1024]
             const float* __restrict__ dWhh,   // [4096][1024]
             const float* __restrict__ dWih,   // [4096][512]
             const float* __restrict__ db,     // [4096]
             const float* __restrict__ xemb,   // [2048][512] trg emb (t*32+b)
             const float* __restrict__ dhin,   // [32][1024]
             float* __restrict__ dcst,         // [32][1024]
             float* __restrict__ dhall_t,      // [32][1024]
             const int* __restrict__ trg, int s)
{
  const int tid = threadIdx.x;
  const int kg  = tid >> 5;
  const int b   = tid & 31;
  __shared__ float4 wl4[2048];     // 32 KB, time-shared
  __shared__ float red[4*16*33];

  if (blockIdx.x < 256) {
    // ---------------- encoder L1 path ----------------
    const int dir = blockIdx.x >> 7;
    const int j0  = (blockIdx.x & 127) * 4;
    {
      const float* W = eWhh + (size_t)dir*2048*512;
      for (int idx = tid; idx < 16*128; idx += 256) {
        int r = idx >> 7, c = idx & 127;
        int g = r >> 2, jj = r & 3;
        wl4[idx] = ((const float4*)(W + (size_t)(g*512 + j0 + jj)*512))[c];
      }
    }
    float4 hreg[16];
    {
      const float4* H4 = (const float4*)(ehin + (size_t)dir*32*512);
      #pragma unroll
      for (int j=0;j<16;j++) hreg[j] = H4[(size_t)b*128 + kg*16 + j];
    }
    __syncthreads();

    float acc[16];
    #pragma unroll
    for (int r=0;r<16;r++) {
      const float4* wr = wl4 + r*128 + kg*16;
      float a0=0.f,a1=0.f,a2=0.f,a3=0.f;
      #pragma unroll
      for (int j=0;j<16;j++) {
        float4 w = wr[j];
        a0 = fmaf(w.x, hreg[j].x, a0);
        a1 = fmaf(w.y, hreg[j].y, a1);
        a2 = fmaf(w.z, hreg[j].z, a2);
        a3 = fmaf(w.w, hreg[j].w, a3);
      }
      acc[r] = (a0+a1)+(a2+a3);
    }
    #pragma unroll
    for (int r=0;r<16;r++) acc[r] += __shfl_xor(acc[r], 32);
    const int wv = tid >> 6;
    if ((tid & 32) == 0) {
      #pragma unroll
      for (int r=0;r<16;r++) red[wv*528 + r*33 + b] = acc[r];
    }
    __syncthreads();

    if (tid < 128) {
      int jj = tid >> 5, bb = tid & 31;
      int jh = j0 + jj;
      int t  = dir ? (63 - s) : s;
      const float* x = xg + ((size_t)t*32 + bb)*4096 + dir*2048;
      float g4[4];
      #pragma unroll
      for (int g=0; g<4; g++) {
        int r = g*4 + jj;
        g4[g] = ((red[0*528 + r*33 + bb] + red[1*528 + r*33 + bb])
               + (red[2*528 + r*33 + bb] + red[3*528 + r*33 + bb]))
               + x[g*512 + jh];
      }
      size_t ci = ((size_t)dir*32 + bb)*512 + jh;
      float cn = sigm(g4[1])*ecst[ci] + sigm(g4[0])*tanhf(g4[2]);
      float hn = sigm(g4[3])*tanhf(cn);
      ecst[ci] = cn;
      ehout[ci] = hn;
      encout[((size_t)bb*64 + t)*1024 + dir*512 + jh] = hn;
    }
  } else {
    // ---------------- decoder path ----------------
    const int j0 = (blockIdx.x - 256) * 4;
    // stage Wih slice (16 rows x 512)
    for (int idx = tid; idx < 16*128; idx += 256) {
      int r = idx >> 7, c = idx & 127;
      int g = r >> 2, jj = r & 3;
      wl4[idx] = ((const float4*)(dWih + (size_t)(g*1024 + j0 + jj)*512))[c];
    }
    float4 xreg[16];
    {
      const float4* X4 = (const float4*)(xemb + (size_t)s*32*512);
      #pragma unroll
      for (int j=0;j<16;j++) xreg[j] = X4[(size_t)b*128 + kg*16 + j];
    }
    float4 hreg[32];
    {
      const float4* H4 = (const float4*)dhin;
      #pragma unroll
      for (int j=0;j<32;j++) hreg[j] = H4[(size_t)b*256 + kg*32 + j];
    }
    __syncthreads();

    float acc[16];
    #pragma unroll
    for (int r=0;r<16;r++) {
      const float4* wr = wl4 + r*128 + kg*16;
      float a0=0.f,a1=0.f,a2=0.f,a3=0.f;
      #pragma unroll
      for (int j=0;j<16;j++) {
        float4 w = wr[j];
        a0 = fmaf(w.x, xreg[j].x, a0);
        a1 = fmaf(w.y, xreg[j].y, a1);
        a2 = fmaf(w.z, xreg[j].z, a2);
        a3 = fmaf(w.w, xreg[j].w, a3);
      }
      acc[r] = (a0+a1)+(a2+a3);
    }
    __syncthreads();
    #pragma unroll
    for (int hh=0; hh<2; hh++) {
      for (int idx = tid; idx < 8*256; idx += 256) {
        int rl = idx >> 8, c = idx & 255;
        int r = hh*8 + rl;
        int g = r >> 2, jj = r & 3;
        wl4[idx] = ((const float4*)(dWhh + (size_t)(g*1024 + j0 + jj)*1024))[c];
      }
      __syncthreads();
      #pragma unroll
      for (int rl=0; rl<8; rl++) {
        const float4* wr = wl4 + rl*256 + kg*32;
        float a0=0.f,a1=0.f,a2=0.f,a3=0.f;
        #pragma unroll
        for (int j=0;j<32;j++) {
          float4 w = wr[j];
          a0 = fmaf(w.x, hreg[j].x, a0);
          a1 = fmaf(w.y, hreg[j].y, a1);
          a2 = fmaf(w.z, hreg[j].z, a2);
          a3 = fmaf(w.w, hreg[j].w, a3);
        }
        acc[hh*8 + rl] += (a0+a1)+(a2+a3);
      }
      __syncthreads();
    }
    #pragma unroll
    for (int r=0;r<16;r++) acc[r] += __shfl_xor(acc[r], 32);
    const int wv = tid >> 6;
    if ((tid & 32) == 0) {
      #pragma unroll
      for (int r=0;r<16;r++) red[wv*528 + r*33 + b] = acc[r];
    }
    __syncthreads();

    if (tid < 128) {
      int jj = tid >> 5, bb = tid & 31;
      int jh = j0 + jj;
      int tgt = trg[bb*TTRG + s + 1];
      bool dm = (tgt == 0);
      float g4[4];
      #pragma unroll
      for (int g=0; g<4; g++) {
        int r = g*4 + jj;
        g4[g] = ((red[0*528 + r*33 + bb] + red[1*528 + r*33 + bb])
               + (red[2*528 + r*33 + bb] + red[3*528 + r*33 + bb]))
               + db[g*1024 + jh];
      }
      size_t ci = (size_t)bb*1024 + jh;
      float cn = sigm(g4[1])*dcst[ci] + sigm(g4[0])*tanhf(g4[2]);
      float hn = sigm(g4[3])*tanhf(cn);
      dcst[ci] = cn;                   // cell NOT masked (matches reference)
      dhall_t[ci] = dm ? 0.f : hn;     // h masked
    }
  }
}

// Pack layer-0 final states into decoder initial h/c
__global__ void k_pack(const float* __restrict__ hfin, const float* __restrict__ cfin,
                       float* __restrict__ dh, float* __restrict__ dcc)
{
  int tid = blockIdx.x*256 + threadIdx.x;   // 32768
  int j = tid & 1023, b = tid >> 10;
  int dir = j >> 9, jj = j & 511;
  size_t si = ((size_t)dir*32 + b)*512 + jj;
  dh[(size_t)b*1024 + j]  = hfin[si];
  dcc[(size_t)b*1024 + j] = cfin[si];
}

// ---------------------------------------------------------------------------
// Batched attention (phase B)
// ---------------------------------------------------------------------------
__global__ __launch_bounds__(256)
void k_attn(const float* __restrict__ Hall,    // [64][32][1024]
            const float* __restrict__ encout,  // [32][64][1024]
            const int* __restrict__ src,
            float* __restrict__ hctx)          // [2048][2048]
{
  int bid = blockIdx.x;
  int t = bid >> 5, b = bid & 31;
  int tid = threadIdx.x;
  __shared__ float sh[1024];
  __shared__ float ssc[64];
  const float* h = Hall + ((size_t)t*32 + b)*1024;
  size_t row = (size_t)t*32 + b;
  #pragma unroll
  for (int r=0;r<4;r++) {
    int jh = tid + 256*r;
    float v = h[jh];
    sh[jh] = v;
    hctx[row*2048 + jh] = v;
  }
  __syncthreads();
  {
    int tq = tid >> 2, part = tid & 3;
    const float* eo = encout + ((size_t)b*64 + tq)*1024 + part*256;
    const float* hh = sh + part*256;
    float s = 0.f;
    for (int k=0;k<256;k++) s = fmaf(hh[k], eo[k], s);
    s += __shfl_xor(s, 1);
    s += __shfl_xor(s, 2);
    if (part == 0) ssc[tq] = (src[b*TSRC + tq] == 0) ? -1e9f : s;
  }
  __syncthreads();
  if (tid < 64) {
    float v = ssc[tid];
    float m = v;
    for (int d=1; d<64; d<<=1) m = fmaxf(m, __shfl_xor(m, d));
    float e = expf(v - m);
    float su = e;
    for (int d=1; d<64; d<<=1) su += __shfl_xor(su, d);
    ssc[tid] = e / su;
  }
  __syncthreads();
  #pragma unroll
  for (int r=0;r<4;r++) {
    int k = tid + 256*r;
    float a = 0.f;
    const float* eb = encout + (size_t)b*65536 + k;
    for (int tt=0;tt<64;tt++) a = fmaf(ssc[tt], eb[tt*1024], a);
    hctx[row*2048 + 1024 + k] = a;
  }
}

// Final: loss = sum(nll)/denom
__global__ __launch_bounds__(256)
void k_final(const float* __restrict__ nll, const int* __restrict__ trg,
             float* __restrict__ outp)
{
  int tid = threadIdx.x;
  __shared__ float ss[256]; __shared__ int sc[256];
  float s = 0.f; int cnt = 0;
  for (int i=tid; i<2048; i+=256) {
    s += nll[i];
    int b = i >> 6, t = (i & 63) + 1;
    cnt += (trg[b*TTRG + t] != 0);
  }
  ss[tid]=s; sc[tid]=cnt; __syncthreads();
  for (int off=128; off; off>>=1) {
    if (tid<off) { ss[tid]+=ss[tid+off]; sc[tid]+=sc[tid+off]; }
    __syncthreads();
  }
  if (tid==0) outp[0] = ss[0] / (float)sc[0];
}

// ---------------------------------------------------------------------------
static void launch_big(hipStream_t st, const float* A, int lda,
                       const float* Bw, int ldb, const float* bias,
                       float* C, int ldc, int M, int N, int K)
{
  int nNb = N/128;
  dim3 g((M/128)*nNb, 1, 1);
  k_gemm128<<<g, dim3(256), 0, st>>>(A, lda, Bw, ldb, bias, C, ldc, K, nNb);
}

static void launch_med(hipStream_t st, const float* A, int lda,
                       const float* Bw, int ldb, const float* bias,
                       float* C, int ldc, int M, int N, int K, int act)
{
  GArgs a;
  a.A=A; a.lda=lda;
  a.Bw=Bw; a.ldb=ldb;
  a.bias=bias;
  a.C=C; a.ldc=ldc;
  a.N=N; a.K=K; a.nNb=(N+63)/64; a.act=act;
  dim3 g((M/64)*a.nNb, 1, 1);
  k_gemm<64,64,16,4,4><<<g, dim3(256), 0, st>>>(a);
}

extern "C" void kernel_launch(void* const* d_in, const int* in_sizes, int n_in,
                              void* d_out, int out_size, void* d_ws, size_t ws_size,
                              hipStream_t stream)
{
  (void)in_sizes; (void)n_in; (void)out_size; (void)ws_size;
  const int*   src   = (const int*)  d_in[0];
  const int*   trg   = (const int*)  d_in[1];
  const float* semb  = (const float*)d_in[2];
  const float* temb  = (const float*)d_in[3];
  const float* e0Wih = (const float*)d_in[4];
  const float* e0Whh = (const float*)d_in[5];
  const float* e0b   = (const float*)d_in[6];
  const float* e1Wih = (const float*)d_in[7];
  const float* e1Whh = (const float*)d_in[8];
  const float* e1b   = (const float*)d_in[9];
  const float* dWih  = (const float*)d_in[10];
  const float* dWhh  = (const float*)d_in[11];
  const float* db    = (const float*)d_in[12];
  const float* W1    = (const float*)d_in[13];
  const float* W2    = (const float*)d_in[14];
  float* out = (float*)d_out;   // f32 output

  float* ws = (float*)d_ws;
  size_t o = 0;
  float* x_in   = ws + o; o += (size_t)2048*512;    // emb; later: zt
  float* xg     = ws + o; o += (size_t)2048*4096;   // xg; later: hctx + partials
  float* x1     = ws + o; o += (size_t)2048*1024;   // layer-1 input; later: Hall
  float* encout = ws + o; o += (size_t)2048*1024;
  float* hA     = ws + o; o += 2*32*512;
  float* hB     = ws + o; o += 2*32*512;
  float* cbuf   = ws + o; o += 2*32*512;
  float* dh0    = ws + o; o += 32*1024;
  float* dc     = ws + o; o += 32*1024;
  float* nll    = ws + o; o += 2048;
  float* Hall   = x1;                        // [64][32][1024]
  float* hctx   = xg;                        // [2048][2048]
  float* zt     = x_in;                      // [2048][512]
  float* Pmax   = xg + (size_t)4*1024*1024;             // [2048][125]
  int*   Parg   = (int*)(Pmax + (size_t)2048*NTILE);    // [2048][125]
  float* Psum   = Pmax + (size_t)2*2048*NTILE;          // [2048][125]
  float* Ltgt   = Pmax + (size_t)3*2048*NTILE;          // [2048]

  // ---- encoder layer 0 ----
  hipMemsetAsync(hA,   0, 2*32*512*sizeof(float), stream);
  hipMemsetAsync(cbuf, 0, 2*32*512*sizeof(float), stream);
  k_gather<<<dim3(2048), dim3(128), 0, stream>>>(semb, src, x_in, TSRC);
  launch_big(stream, x_in, 512, e0Wih, 512, e0b, xg, 4096, 2048, 4096, 512);
  for (int s=0; s<64; s++) {
    float* hin  = (s&1) ? hB : hA;
    float* hout = (s&1) ? hA : hB;
    k_estep<<<dim3(256), dim3(256), 0, stream>>>(e0Whh, xg, hin, hout, cbuf, x1, s);
  }
  k_pack<<<dim3(128), dim3(256), 0, stream>>>(hA, cbuf, dh0, dc);

  // ---- prep: enc L1 input gates (xg) + decoder trg embeddings (x_in) ----
  hipMemsetAsync(hA,   0, 2*32*512*sizeof(float), stream);
  hipMemsetAsync(cbuf, 0, 2*32*512*sizeof(float), stream);
  launch_big(stream, x1, 1024, e1Wih, 1024, e1b, xg, 4096, 2048, 4096, 1024);
  k_gather<<<dim3(2048), dim3(128), 0, stream>>>(temb, trg, x_in, TTRG);

  // ---- MERGED loop: enc L1 step s (blocks 0-255) + dec step s (256-511) ----
  for (int s=0; s<64; s++) {
    float* ehin  = (s&1) ? hB : hA;
    float* ehout = (s&1) ? hA : hB;
    const float* dhin = (s == 0) ? dh0 : (Hall + (size_t)(s-1)*32*1024);
    k_mstep<<<dim3(512), dim3(256), 0, stream>>>(
        e1Whh, xg, ehin, ehout, cbuf, encout,
        dWhh, dWih, db, x_in, dhin, dc, Hall + (size_t)s*32*1024, trg, s);
  }

  // ---- decoder phase B: batched attention + projections + fused logits ----
  k_attn<<<dim3(2048), dim3(256), 0, stream>>>(Hall, encout, src, hctx);
  launch_med(stream, hctx, 2048, W1, 2048, nullptr, zt, 512, 2048, 512, 2048, 1);
  k_logits<<<dim3(2048), dim3(256), 0, stream>>>(zt, W2, trg, Pmax, Parg, Psum, Ltgt);
  k_combine<<<dim3(2048), dim3(128), 0, stream>>>(Pmax, Parg, Psum, Ltgt, trg, nll, out);
  k_final<<<dim3(1), dim3(256), 0, stream>>>(nll, trg, out);
}

// Round 16
// 4406.384 us; speedup vs baseline: 1.0761x; 1.0761x over previous
//
#include <hip/hip_runtime.h>
#include <hip/hip_bf16.h>
#include <math.h>

// Problem constants (B=32, Ts=64, Tt=66, E=H=512, V=16000)
#define TSRC 64
#define TTRG 66
#define NVOC 15996   // V-4
#define NTILE 125    // ceil(15996/128)

__device__ __forceinline__ float sigm(float x){ return 1.f/(1.f+expf(-x)); }

// ---------------------------------------------------------------------------
// Input GEMM 128x128 tile, conflict-free dual-float4 fragments,
// register-staged double-buffered LDS (1 barrier/tile).
// ---------------------------------------------------------------------------
__global__ __launch_bounds__(256)
void k_gemm128(const float* __restrict__ A, int lda,
               const float* __restrict__ Bw, int ldb,
               const float* __restrict__ bias,
               float* __restrict__ C, int ldc, int K, int nNb)
{
  const int tid = threadIdx.x;
  const int mb = blockIdx.x / nNb;
  const int nb = blockIdx.x % nNb;
  const int m0 = mb*128, n0 = nb*128;

  __shared__ alignas(16) float As[2][16][132];
  __shared__ alignas(16) float Bs[2][16][132];
  const int tx = tid & 15;
  const int ty = tid >> 4;
  const int sm_ = tid >> 4;      // staged row/col index (0..127 via q)
  const int sk_ = tid & 15;
  float acc[8][8];
  #pragma unroll
  for (int i=0;i<8;i++)
    #pragma unroll
    for (int j=0;j<8;j++) acc[i][j]=0.f;

  // prologue: stage tile 0 into buffer 0
  #pragma unroll
  for (int q=0;q<8;q++) {
    int m = sm_ + 16*q;
    As[0][sk_][m] = A[(size_t)(m0+m)*lda + sk_];
    Bs[0][sk_][m] = Bw[(size_t)(n0+m)*ldb + sk_];
  }
  __syncthreads();

  const int NT = K >> 4;
  for (int t=0; t<NT; ++t) {
    int cur = t & 1, nxt = cur^1;
    float aR[8], bR[8];
    if (t+1 < NT) {
      int kt = (t+1)<<4;
      #pragma unroll
      for (int q=0;q<8;q++) {
        int m = sm_ + 16*q;
        aR[q] = A[(size_t)(m0+m)*lda + kt + sk_];
        bR[q] = Bw[(size_t)(n0+m)*ldb + kt + sk_];
      }
    }
    #pragma unroll
    for (int k=0;k<16;k++) {
      float4 a0 = *reinterpret_cast<const float4*>(&As[cur][k][ty*4]);
      float4 a1 = *reinterpret_cast<const float4*>(&As[cur][k][64+ty*4]);
      float4 b0 = *reinterpret_cast<const float4*>(&Bs[cur][k][tx*4]);
      float4 b1 = *reinterpret_cast<const float4*>(&Bs[cur][k][64+tx*4]);
      float av[8] = {a0.x,a0.y,a0.z,a0.w,a1.x,a1.y,a1.z,a1.w};
      float bv[8] = {b0.x,b0.y,b0.z,b0.w,b1.x,b1.y,b1.z,b1.w};
      #pragma unroll
      for (int i=0;i<8;i++)
        #pragma unroll
        for (int j=0;j<8;j++)
          acc[i][j] = fmaf(av[i], bv[j], acc[i][j]);
    }
    if (t+1 < NT) {
      #pragma unroll
      for (int q=0;q<8;q++) {
        int m = sm_ + 16*q;
        As[nxt][sk_][m] = aR[q];
        Bs[nxt][sk_][m] = bR[q];
      }
    }
    __syncthreads();
  }
  #pragma unroll
  for (int i=0;i<8;i++) {
    int m = m0 + ((i<4) ? ty*4+i : 64+ty*4+(i-4));
    int nA = n0 + tx*4, nB = n0 + 64 + tx*4;
    float4 v0, v1;
    v0.x = acc[i][0] + (bias?bias[nA+0]:0.f);
    v0.y = acc[i][1] + (bias?bias[nA+1]:0.f);
    v0.z = acc[i][2] + (bias?bias[nA+2]:0.f);
    v0.w = acc[i][3] + (bias?bias[nA+3]:0.f);
    v1.x = acc[i][4] + (bias?bias[nB+0]:0.f);
    v1.y = acc[i][5] + (bias?bias[nB+1]:0.f);
    v1.z = acc[i][6] + (bias?bias[nB+2]:0.f);
    v1.w = acc[i][7] + (bias?bias[nB+3]:0.f);
    *reinterpret_cast<float4*>(&C[(size_t)m*ldc + nA]) = v0;
    *reinterpret_cast<float4*>(&C[(size_t)m*ldc + nB]) = v1;
  }
}

// ---------------------------------------------------------------------------
// Fused logits GEMM + per-tile row reduction, conflict-free fragments,
// register-staged double-buffered LDS. XCD-swizzled.
// ---------------------------------------------------------------------------
__global__ __launch_bounds__(256)
void k_logits(const float* __restrict__ A, const float* __restrict__ Bw,
              const int* __restrict__ trg,
              float* __restrict__ Pmax, int* __restrict__ Parg,
              float* __restrict__ Psum, float* __restrict__ Ltgt)
{
  const int tid = threadIdx.x;
  const int j8   = blockIdx.x & 7;
  const int mb   = (blockIdx.x >> 3) & 15;
  const int nb   = ((blockIdx.x >> 7) << 3) + j8;
  if (nb >= NTILE) return;
  const int m0 = mb*128, n0 = nb*128;

  __shared__ alignas(16) float As[2][16][132];
  __shared__ alignas(16) float Bs[2][16][132];
  const int tx = tid & 15;
  const int ty = tid >> 4;
  const int sm_ = tid >> 4;
  const int sk_ = tid & 15;
  float acc[8][8];
  #pragma unroll
  for (int i=0;i<8;i++)
    #pragma unroll
    for (int j=0;j<8;j++) acc[i][j]=0.f;

  #pragma unroll
  for (int q=0;q<8;q++) {
    int m = sm_ + 16*q;
    int gn = n0 + m;
    As[0][sk_][m] = A[(size_t)(m0+m)*512 + sk_];
    Bs[0][sk_][m] = (gn < NVOC) ? Bw[(size_t)gn*512 + sk_] : 0.f;
  }
  __syncthreads();

  for (int t=0; t<32; ++t) {
    int cur = t & 1, nxt = cur^1;
    float aR[8], bR[8];
    if (t+1 < 32) {
      int kt = (t+1)<<4;
      #pragma unroll
      for (int q=0;q<8;q++) {
        int m = sm_ + 16*q;
        int gn = n0 + m;
        aR[q] = A[(size_t)(m0+m)*512 + kt + sk_];
        bR[q] = (gn < NVOC) ? Bw[(size_t)gn*512 + kt + sk_] : 0.f;
      }
    }
    #pragma unroll
    for (int k=0;k<16;k++) {
      float4 a0 = *reinterpret_cast<const float4*>(&As[cur][k][ty*4]);
      float4 a1 = *reinterpret_cast<const float4*>(&As[cur][k][64+ty*4]);
      float4 b0 = *reinterpret_cast<const float4*>(&Bs[cur][k][tx*4]);
      float4 b1 = *reinterpret_cast<const float4*>(&Bs[cur][k][64+tx*4]);
      float av[8] = {a0.x,a0.y,a0.z,a0.w,a1.x,a1.y,a1.z,a1.w};
      float bv[8] = {b0.x,b0.y,b0.z,b0.w,b1.x,b1.y,b1.z,b1.w};
      #pragma unroll
      for (int i=0;i<8;i++)
        #pragma unroll
        for (int j=0;j<8;j++)
          acc[i][j] = fmaf(av[i], bv[j], acc[i][j]);
    }
    if (t+1 < 32) {
      #pragma unroll
      for (int q=0;q<8;q++) {
        int m = sm_ + 16*q;
        As[nxt][sk_][m] = aR[q];
        Bs[nxt][sk_][m] = bR[q];
      }
    }
    __syncthreads();
  }

  #pragma unroll
  for (int i=0;i<8;i++) {
    int r = m0 + ((i<4) ? ty*4+i : 64+ty*4+(i-4));   // row = step*32 + b
    int step = r >> 5, b = r & 31;
    int tgt = trg[b*TTRG + step + 1];
    int ti = tgt - 4;
    float m = -3.4e38f; int am = 0x7fffffff;
    #pragma unroll
    for (int j=0;j<8;j++) {
      int gn = n0 + ((j<4) ? tx*4+j : 64+tx*4+(j-4));
      if (gn < NVOC) {
        float x = acc[i][j];
        if (x > m || (x == m && gn < am)) { m = x; am = gn; }
      }
    }
    float s = 0.f;
    float lt = 0.f;
    #pragma unroll
    for (int j=0;j<8;j++) {
      int gn = n0 + ((j<4) ? tx*4+j : 64+tx*4+(j-4));
      if (gn < NVOC) {
        s += expf(acc[i][j] - m);
        if (gn == ti) lt = acc[i][j];
      }
    }
    #pragma unroll
    for (int d=1; d<16; d<<=1) {
      float m2 = __shfl_xor(m, d);
      int   a2 = __shfl_xor(am, d);
      float s2 = __shfl_xor(s, d);
      float l2 = __shfl_xor(lt, d);
      float M = fmaxf(m, m2);
      s = s*expf(m - M) + s2*expf(m2 - M);
      if (m2 > m || (m2 == m && a2 < am)) am = a2;
      m = M;
      lt += l2;
    }
    if (tx == 0) {
      size_t pi = (size_t)r*NTILE + nb;
      Pmax[pi] = m; Parg[pi] = am; Psum[pi] = s;
      if (ti >= n0 && ti < n0 + 128) Ltgt[r] = lt;
    }
  }
}

// ---------------------------------------------------------------------------
// Tiled GEMM (64x64, used for W1 only): C = A*B^T, tanh epilogue.
// ---------------------------------------------------------------------------
struct GArgs {
  const float* A;  int lda;
  const float* Bw; int ldb;
  const float* bias;
  float* C; int ldc;
  int N; int K; int nNb; int act;
};

template<int BM,int BN,int BK,int TM,int TN>
__global__ __launch_bounds__(256)
void k_gemm(GArgs a)
{
  const int tid = threadIdx.x;
  const int mb = blockIdx.x / a.nNb;
  const int nb = blockIdx.x % a.nNb;
  const int m0 = mb*BM, n0 = nb*BN;
  const float* A  = a.A + (size_t)m0*a.lda;
  const float* Bw = a.Bw;

  __shared__ float As[BK][BM+1];
  __shared__ float Bs[BK][BN+4];
  const int tx = tid % (BN/TN);
  const int ty = tid / (BN/TN);
  float acc[TM][TN];
  #pragma unroll
  for (int i=0;i<TM;i++)
    #pragma unroll
    for (int j=0;j<TN;j++) acc[i][j]=0.f;

  for (int kt=0; kt<a.K; kt+=BK) {
    #pragma unroll
    for (int i=tid; i<BM*BK; i+=256) {
      int m = i/BK, k = i%BK;
      As[k][m] = A[(size_t)m*a.lda + kt + k];
    }
    #pragma unroll
    for (int i=tid; i<BN*BK; i+=256) {
      int n = i/BK, k = i%BK;
      int gn = n0+n;
      Bs[k][n] = (gn < a.N) ? Bw[(size_t)gn*a.ldb + kt + k] : 0.f;
    }
    __syncthreads();
    #pragma unroll
    for (int k=0;k<BK;k++) {
      float av[TM], bv[TN];
      #pragma unroll
      for (int i=0;i<TM;i++) av[i]=As[k][ty*TM+i];
      #pragma unroll
      for (int j=0;j<TN;j++) bv[j]=Bs[k][tx*TN+j];
      #pragma unroll
      for (int i=0;i<TM;i++)
        #pragma unroll
        for (int j=0;j<TN;j++)
          acc[i][j] = fmaf(av[i], bv[j], acc[i][j]);
    }
    __syncthreads();
  }
  #pragma unroll
  for (int i=0;i<TM;i++) {
    int m = m0 + ty*TM + i;
    #pragma unroll
    for (int j=0;j<TN;j++) {
      int n = n0 + tx*TN + j;
      if (n < a.N) {
        float v = acc[i][j];
        if (a.bias) v += a.bias[n];
        if (a.act)  v = tanhf(v);
        a.C[(size_t)m*a.ldc + n] = v;
      }
    }
  }
}

// Combine per-tile partials -> nll + pred per row.
__global__ __launch_bounds__(128)
void k_combine(const float* __restrict__ Pmax, const int* __restrict__ Parg,
               const float* __restrict__ Psum, const float* __restrict__ Ltgt,
               const int* __restrict__ trg,
               float* __restrict__ nll, float* __restrict__ outp)
{
  int r = blockIdx.x;
  int step = r >> 5, b = r & 31;
  int tid = threadIdx.x;
  __shared__ float sm[128]; __shared__ int sa[128]; __shared__ float ssum[128];
  float m = -3.4e38f; int am = 0x7fffffff; float s = 0.f;
  if (tid < NTILE) {
    size_t pi = (size_t)r*NTILE + tid;
    m = Pmax[pi]; am = Parg[pi]; s = Psum[pi];
  }
  sm[tid]=m; sa[tid]=am; ssum[tid]=s; __syncthreads();
  for (int off=64; off; off>>=1) {
    if (tid < off) {
      float m2 = sm[tid+off]; int a2 = sa[tid+off]; float s2 = ssum[tid+off];
      float m1 = sm[tid];     int a1 = sa[tid];     float s1 = ssum[tid];
      float M = fmaxf(m1, m2);
      ssum[tid] = s1*expf(m1 - M) + s2*expf(m2 - M);
      if (m2 > m1 || (m2 == m1 && a2 < a1)) sa[tid] = a2;
      sm[tid] = M;
    }
    __syncthreads();
  }
  if (tid == 0) {
    int tgt = trg[b*TTRG + step + 1];
    float nl = 0.f;
    if (tgt != 0) nl = -(Ltgt[r] - sm[0] - logf(ssum[0]));
    nll[step*32 + b] = nl;
    outp[1 + b*64 + step] = (float)(sa[0] + 4);
  }
}

// Embedding gather
__global__ void k_gather(const float* __restrict__ emb, const int* __restrict__ tok,
                         float* __restrict__ outp, int Tfull)
{
  int r = blockIdx.x;
  int t = r >> 5, b = r & 31;
  int token = tok[b*Tfull + t];
  const float4* s = (const float4*)(emb + (size_t)token*512);
  float4* d = (float4*)(outp + (size_t)r*512);
  d[threadIdx.x] = s[threadIdx.x];
}

// ---------------------------------------------------------------------------
// FUSED encoder LSTM step (ONE launch): full-K gates + update + scatter.
// ---------------------------------------------------------------------------
__global__ __launch_bounds__(256)
void k_estep(const float* __restrict__ Whh,   // [2][2048][512]
             const float* __restrict__ xg,    // [2048][4096]
             const float* __restrict__ hin,   // [2*32][512]
             float* __restrict__ hout,        // [2*32][512]
             float* __restrict__ cst,         // [2*32][512]
             float* __restrict__ xout, int s, int mode)
{
  const int bid = blockIdx.x;
  const int dir = bid >> 7;
  const int j0  = (bid & 127) * 4;
  const int tid = threadIdx.x;
  const int kg  = tid >> 5;
  const int b   = tid & 31;
  __shared__ float4 wl4[16*128];
  __shared__ float red[4*16*33];

  {
    const float* W = Whh + (size_t)dir*2048*512;
    for (int idx = tid; idx < 16*128; idx += 256) {
      int r = idx >> 7, c = idx & 127;
      int g = r >> 2, jj = r & 3;
      wl4[idx] = ((const float4*)(W + (size_t)(g*512 + j0 + jj)*512))[c];
    }
  }
  float4 hreg[16];
  {
    const float4* H4 = (const float4*)(hin + (size_t)dir*32*512);
    #pragma unroll
    for (int j=0;j<16;j++) hreg[j] = H4[(size_t)b*128 + kg*16 + j];
  }
  __syncthreads();

  float acc[16];
  #pragma unroll
  for (int r=0;r<16;r++) {
    const float4* wr = wl4 + r*128 + kg*16;
    float a0=0.f,a1=0.f,a2=0.f,a3=0.f;
    #pragma unroll
    for (int j=0;j<16;j++) {
      float4 w = wr[j];
      a0 = fmaf(w.x, hreg[j].x, a0);
      a1 = fmaf(w.y, hreg[j].y, a1);
      a2 = fmaf(w.z, hreg[j].z, a2);
      a3 = fmaf(w.w, hreg[j].w, a3);
    }
    acc[r] = (a0+a1)+(a2+a3);
  }
  #pragma unroll
  for (int r=0;r<16;r++) acc[r] += __shfl_xor(acc[r], 32);
  const int wv = tid >> 6;
  if ((tid & 32) == 0) {
    #pragma unroll
    for (int r=0;r<16;r++) red[wv*528 + r*33 + b] = acc[r];
  }
  __syncthreads();

  if (tid < 128) {
    int jj = tid >> 5, bb = tid & 31;
    int jh = j0 + jj;
    int t  = dir ? (63 - s) : s;
    const float* x = xg + ((size_t)t*32 + bb)*4096 + dir*2048;
    float g4[4];
    #pragma unroll
    for (int g=0; g<4; g++) {
      int r = g*4 + jj;
      g4[g] = ((red[0*528 + r*33 + bb] + red[1*528 + r*33 + bb])
             + (red[2*528 + r*33 + bb] + red[3*528 + r*33 + bb]))
             + x[g*512 + jh];
    }
    size_t ci = ((size_t)dir*32 + bb)*512 + jh;
    float cn = sigm(g4[1])*cst[ci] + sigm(g4[0])*tanhf(g4[2]);
    float hn = sigm(g4[3])*tanhf(cn);
    cst[ci] = cn;
    hout[ci] = hn;
    if (mode == 0) xout[((size_t)t*32 + bb)*1024 + dir*512 + jh] = hn;  // x1
    else           xout[((size_t)bb*64 + t)*1024 + dir*512 + jh] = hn;  // enc_out
  }
}

// ---------------------------------------------------------------------------
// FUSED decoder LSTM step (ONE launch): full-K gates + update + mask -> Hall.
// ---------------------------------------------------------------------------
__global__ __launch_bounds__(256)
void k_dstep(const float* __restrict__ Whh,   // [4096][1024]
             const float* __restrict__ xg_t,  // [32][4096] this step
             const float* __restrict__ hin,   // [32][1024]
             float* __restrict__ cst,         // [32][1024]
             float* __restrict__ hall_t,      // [32][1024]
             const int* __restrict__ trg, int st)
{
  const int bid = blockIdx.x;
  const int j0  = bid*4;
  const int tid = threadIdx.x;
  const int kg  = tid >> 5;
  const int b   = tid & 31;
  __shared__ float4 wl4[8*256];
  __shared__ float red[4*16*33];

  float4 hreg[32];
  {
    const float4* H4 = (const float4*)hin;
    #pragma unroll
    for (int j=0;j<32;j++) hreg[j] = H4[(size_t)b*256 + kg*32 + j];
  }

  float acc[16];
  #pragma unroll
  for (int hh=0; hh<2; hh++) {
    for (int idx = tid; idx < 8*256; idx += 256) {
      int rl = idx >> 8, c = idx & 255;
      int r = hh*8 + rl;
      int g = r >> 2, jj = r & 3;
      wl4[idx] = ((const float4*)(Whh + (size_t)(g*1024 + j0 + jj)*1024))[c];
    }
    __syncthreads();
    #pragma unroll
    for (int rl=0; rl<8; rl++) {
      const float4* wr = wl4 + rl*256 + kg*32;
      float a0=0.f,a1=0.f,a2=0.f,a3=0.f;
      #pragma unroll
      for (int j=0;j<32;j++) {
        float4 w = wr[j];
        a0 = fmaf(w.x, hreg[j].x, a0);
        a1 = fmaf(w.y, hreg[j].y, a1);
        a2 = fmaf(w.z, hreg[j].z, a2);
        a3 = fmaf(w.w, hreg[j].w, a3);
      }
      acc[hh*8 + rl] = (a0+a1)+(a2+a3);
    }
    __syncthreads();
  }
  #pragma unroll
  for (int r=0;r<16;r++) acc[r] += __shfl_xor(acc[r], 32);
  const int wv = tid >> 6;
  if ((tid & 32) == 0) {
    #pragma unroll
    for (int r=0;r<16;r++) red[wv*528 + r*33 + b] = acc[r];
  }
  __syncthreads();

  if (tid < 128) {
    int jj = tid >> 5, bb = tid & 31;
    int jh = j0 + jj;
    int tgt = trg[bb*TTRG + st + 1];
    bool dm = (tgt == 0);
    const float* x = xg_t + (size_t)bb*4096;
    float g4[4];
    #pragma unroll
    for (int g=0; g<4; g++) {
      int r = g*4 + jj;
      g4[g] = ((red[0*528 + r*33 + bb] + red[1*528 + r*33 + bb])
             + (red[2*528 + r*33 + bb] + red[3*528 + r*33 + bb]))
             + x[g*1024 + jh];
    }
    size_t ci = (size_t)bb*1024 + jh;
    float cn = sigm(g4[1])*cst[ci] + sigm(g4[0])*tanhf(g4[2]);
    float hn = sigm(g4[3])*tanhf(cn);
    cst[ci] = cn;                    // cell NOT masked (matches reference)
    hall_t[ci] = dm ? 0.f : hn;      // h masked
  }
}

// Pack layer-0 final states into decoder initial h/c
__global__ void k_pack(const float* __restrict__ hfin, const float* __restrict__ cfin,
                       float* __restrict__ dh, float* __restrict__ dcc)
{
  int tid = blockIdx.x*256 + threadIdx.x;   // 32768
  int j = tid & 1023, b = tid >> 10;
  int dir = j >> 9, jj = j & 511;
  size_t si = ((size_t)dir*32 + b)*512 + jj;
  dh[(size_t)b*1024 + j]  = hfin[si];
  dcc[(size_t)b*1024 + j] = cfin[si];
}

// ---------------------------------------------------------------------------
// Batched attention (phase B)
// ---------------------------------------------------------------------------
__global__ __launch_bounds__(256)
void k_attn(const float* __restrict__ Hall,    // [64][32][1024]
            const float* __restrict__ encout,  // [32][64][1024]
            const int* __restrict__ src,
            float* __restrict__ hctx)          // [2048][2048]
{
  int bid = blockIdx.x;
  int t = bid >> 5, b = bid & 31;
  int tid = threadIdx.x;
  __shared__ float sh[1024];
  __shared__ float ssc[64];
  const float* h = Hall + ((size_t)t*32 + b)*1024;
  size_t row = (size_t)t*32 + b;
  #pragma unroll
  for (int r=0;r<4;r++) {
    int jh = tid + 256*r;
    float v = h[jh];
    sh[jh] = v;
    hctx[row*2048 + jh] = v;
  }
  __syncthreads();
  {
    int tq = tid >> 2, part = tid & 3;
    const float* eo = encout + ((size_t)b*64 + tq)*1024 + part*256;
    const float* hh = sh + part*256;
    float s = 0.f;
    for (int k=0;k<256;k++) s = fmaf(hh[k], eo[k], s);
    s += __shfl_xor(s, 1);
    s += __shfl_xor(s, 2);
    if (part == 0) ssc[tq] = (src[b*TSRC + tq] == 0) ? -1e9f : s;
  }
  __syncthreads();
  if (tid < 64) {
    float v = ssc[tid];
    float m = v;
    for (int d=1; d<64; d<<=1) m = fmaxf(m, __shfl_xor(m, d));
    float e = expf(v - m);
    float su = e;
    for (int d=1; d<64; d<<=1) su += __shfl_xor(su, d);
    ssc[tid] = e / su;
  }
  __syncthreads();
  #pragma unroll
  for (int r=0;r<4;r++) {
    int k = tid + 256*r;
    float a = 0.f;
    const float* eb = encout + (size_t)b*65536 + k;
    for (int tt=0;tt<64;tt++) a = fmaf(ssc[tt], eb[tt*1024], a);
    hctx[row*2048 + 1024 + k] = a;
  }
}

// Final: loss = sum(nll)/denom
__global__ __launch_bounds__(256)
void k_final(const float* __restrict__ nll, const int* __restrict__ trg,
             float* __restrict__ outp)
{
  int tid = threadIdx.x;
  __shared__ float ss[256]; __shared__ int sc[256];
  float s = 0.f; int cnt = 0;
  for (int i=tid; i<2048; i+=256) {
    s += nll[i];
    int b = i >> 6, t = (i & 63) + 1;
    cnt += (trg[b*TTRG + t] != 0);
  }
  ss[tid]=s; sc[tid]=cnt; __syncthreads();
  for (int off=128; off; off>>=1) {
    if (tid<off) { ss[tid]+=ss[tid+off]; sc[tid]+=sc[tid+off]; }
    __syncthreads();
  }
  if (tid==0) outp[0] = ss[0] / (float)sc[0];
}

// ---------------------------------------------------------------------------
static void launch_big(hipStream_t st, const float* A, int lda,
                       const float* Bw, int ldb, const float* bias,
                       float* C, int ldc, int M, int N, int K)
{
  int nNb = N/128;
  dim3 g((M/128)*nNb, 1, 1);
  k_gemm128<<<g, dim3(256), 0, st>>>(A, lda, Bw, ldb, bias, C, ldc, K, nNb);
}

static void launch_med(hipStream_t st, const float* A, int lda,
                       const float* Bw, int ldb, const float* bias,
                       float* C, int ldc, int M, int N, int K, int act)
{
  GArgs a;
  a.A=A; a.lda=lda;
  a.Bw=Bw; a.ldb=ldb;
  a.bias=bias;
  a.C=C; a.ldc=ldc;
  a.N=N; a.K=K; a.nNb=(N+63)/64; a.act=act;
  dim3 g((M/64)*a.nNb, 1, 1);
  k_gemm<64,64,16,4,4><<<g, dim3(256), 0, st>>>(a);
}

extern "C" void kernel_launch(void* const* d_in, const int* in_sizes, int n_in,
                              void* d_out, int out_size, void* d_ws, size_t ws_size,
                              hipStream_t stream)
{
  (void)in_sizes; (void)n_in; (void)out_size; (void)ws_size;
  const int*   src   = (const int*)  d_in[0];
  const int*   trg   = (const int*)  d_in[1];
  const float* semb  = (const float*)d_in[2];
  const float* temb  = (const float*)d_in[3];
  const float* e0Wih = (const float*)d_in[4];
  const float* e0Whh = (const float*)d_in[5];
  const float* e0b   = (const float*)d_in[6];
  const float* e1Wih = (const float*)d_in[7];
  const float* e1Whh = (const float*)d_in[8];
  const float* e1b   = (const float*)d_in[9];
  const float* dWih  = (const float*)d_in[10];
  const float* dWhh  = (const float*)d_in[11];
  const float* db    = (const float*)d_in[12];
  const float* W1    = (const float*)d_in[13];
  const float* W2    = (const float*)d_in[14];
  float* out = (float*)d_out;   // f32 output

  float* ws = (float*)d_ws;
  size_t o = 0;
  float* x_in   = ws + o; o += (size_t)2048*512;    // emb; later: zt
  float* xg     = ws + o; o += (size_t)2048*4096;   // xg; later: hctx + partials
  float* x1     = ws + o; o += (size_t)2048*1024;   // layer-1 input; later: Hall
  float* encout = ws + o; o += (size_t)2048*1024;
  float* hA     = ws + o; o += 2*32*512;
  float* hB     = ws + o; o += 2*32*512;
  float* cbuf   = ws + o; o += 2*32*512;
  float* dh0    = ws + o; o += 32*1024;
  float* dc     = ws + o; o += 32*1024;
  float* nll    = ws + o; o += 2048;
  float* Hall   = x1;                        // [64][32][1024]
  float* hctx   = xg;                        // [2048][2048]
  float* zt     = x_in;                      // [2048][512]
  float* Pmax   = xg + (size_t)4*1024*1024;             // [2048][125]
  int*   Parg   = (int*)(Pmax + (size_t)2048*NTILE);    // [2048][125]
  float* Psum   = Pmax + (size_t)2*2048*NTILE;          // [2048][125]
  float* Ltgt   = Pmax + (size_t)3*2048*NTILE;          // [2048]

  // ---- encoder layer 0 ----
  hipMemsetAsync(hA,   0, 2*32*512*sizeof(float), stream);
  hipMemsetAsync(cbuf, 0, 2*32*512*sizeof(float), stream);
  k_gather<<<dim3(2048), dim3(128), 0, stream>>>(semb, src, x_in, TSRC);
  launch_big(stream, x_in, 512, e0Wih, 512, e0b, xg, 4096, 2048, 4096, 512);
  for (int s=0; s<64; s++) {
    float* hin  = (s&1) ? hB : hA;
    float* hout = (s&1) ? hA : hB;
    k_estep<<<dim3(256), dim3(256), 0, stream>>>(e0Whh, xg, hin, hout, cbuf, x1, s, 0);
  }
  k_pack<<<dim3(128), dim3(256), 0, stream>>>(hA, cbuf, dh0, dc);

  // ---- encoder layer 1 ----
  hipMemsetAsync(hA,   0, 2*32*512*sizeof(float), stream);
  hipMemsetAsync(cbuf, 0, 2*32*512*sizeof(float), stream);
  launch_big(stream, x1, 1024, e1Wih, 1024, e1b, xg, 4096, 2048, 4096, 1024);
  for (int s=0; s<64; s++) {
    float* hin  = (s&1) ? hB : hA;
    float* hout = (s&1) ? hA : hB;
    k_estep<<<dim3(256), dim3(256), 0, stream>>>(e1Whh, xg, hin, hout, cbuf, encout, s, 1);
  }

  // ---- decoder phase A: sequential recurrence into Hall (1 launch/step) ----
  k_gather<<<dim3(2048), dim3(128), 0, stream>>>(temb, trg, x_in, TTRG);
  launch_big(stream, x_in, 512, dWih, 512, db, xg, 4096, 2048, 4096, 512);
  for (int st=0; st<64; st++) {
    const float* hin = (st == 0) ? dh0 : (Hall + (size_t)(st-1)*32*1024);
    k_dstep<<<dim3(256), dim3(256), 0, stream>>>(dWhh, xg + (size_t)st*32*4096,
                 hin, dc, Hall + (size_t)st*32*1024, trg, st);
  }

  // ---- decoder phase B: batched attention + projections + fused logits ----
  k_attn<<<dim3(2048), dim3(256), 0, stream>>>(Hall, encout, src, hctx);
  launch_med(stream, hctx, 2048, W1, 2048, nullptr, zt, 512, 2048, 512, 2048, 1);
  k_logits<<<dim3(2048), dim3(256), 0, stream>>>(zt, W2, trg, Pmax, Parg, Psum, Ltgt);
  k_combine<<<dim3(2048), dim3(128), 0, stream>>>(Pmax, Parg, Psum, Ltgt, trg, nll, out);
  k_final<<<dim3(1), dim3(256), 0, stream>>>(nll, trg, out);
}

// Round 17
// 4077.849 us; speedup vs baseline: 1.1628x; 1.0806x over previous
//
#include <hip/hip_runtime.h>
#include <hip/hip_bf16.h>
#include <math.h>

// Problem constants (B=32, Ts=64, Tt=66, E=H=512, V=16000)
#define TSRC 64
#define TTRG 66
#define NVOC 15996   // V-4
#define NTILE 125    // ceil(15996/128)

__device__ __forceinline__ float sigm(float x){ return 1.f/(1.f+expf(-x)); }

// ---------------------------------------------------------------------------
// Input GEMM 128x128 tile, conflict-free dual-float4 fragments (R14-proven).
// ---------------------------------------------------------------------------
__global__ __launch_bounds__(256)
void k_gemm128(const float* __restrict__ A, int lda,
               const float* __restrict__ Bw, int ldb,
               const float* __restrict__ bias,
               float* __restrict__ C, int ldc, int K, int nNb)
{
  const int tid = threadIdx.x;
  const int mb = blockIdx.x / nNb;
  const int nb = blockIdx.x % nNb;
  const int m0 = mb*128, n0 = nb*128;

  __shared__ alignas(16) float As[16][132];
  __shared__ alignas(16) float Bs[16][132];
  const int tx = tid & 15;
  const int ty = tid >> 4;
  float acc[8][8];
  #pragma unroll
  for (int i=0;i<8;i++)
    #pragma unroll
    for (int j=0;j<8;j++) acc[i][j]=0.f;

  for (int kt=0; kt<K; kt+=16) {
    #pragma unroll
    for (int i=tid; i<128*16; i+=256) {
      int m = i>>4, k = i&15;
      As[k][m] = A[(size_t)(m0+m)*lda + kt + k];
    }
    #pragma unroll
    for (int i=tid; i<128*16; i+=256) {
      int n = i>>4, k = i&15;
      Bs[k][n] = Bw[(size_t)(n0+n)*ldb + kt + k];
    }
    __syncthreads();
    #pragma unroll
    for (int k=0;k<16;k++) {
      float4 a0 = *reinterpret_cast<const float4*>(&As[k][ty*4]);
      float4 a1 = *reinterpret_cast<const float4*>(&As[k][64+ty*4]);
      float4 b0 = *reinterpret_cast<const float4*>(&Bs[k][tx*4]);
      float4 b1 = *reinterpret_cast<const float4*>(&Bs[k][64+tx*4]);
      float av[8] = {a0.x,a0.y,a0.z,a0.w,a1.x,a1.y,a1.z,a1.w};
      float bv[8] = {b0.x,b0.y,b0.z,b0.w,b1.x,b1.y,b1.z,b1.w};
      #pragma unroll
      for (int i=0;i<8;i++)
        #pragma unroll
        for (int j=0;j<8;j++)
          acc[i][j] = fmaf(av[i], bv[j], acc[i][j]);
    }
    __syncthreads();
  }
  #pragma unroll
  for (int i=0;i<8;i++) {
    int m = m0 + ((i<4) ? ty*4+i : 64+ty*4+(i-4));
    int nA = n0 + tx*4, nB = n0 + 64 + tx*4;
    float4 v0, v1;
    v0.x = acc[i][0] + (bias?bias[nA+0]:0.f);
    v0.y = acc[i][1] + (bias?bias[nA+1]:0.f);
    v0.z = acc[i][2] + (bias?bias[nA+2]:0.f);
    v0.w = acc[i][3] + (bias?bias[nA+3]:0.f);
    v1.x = acc[i][4] + (bias?bias[nB+0]:0.f);
    v1.y = acc[i][5] + (bias?bias[nB+1]:0.f);
    v1.z = acc[i][6] + (bias?bias[nB+2]:0.f);
    v1.w = acc[i][7] + (bias?bias[nB+3]:0.f);
    *reinterpret_cast<float4*>(&C[(size_t)m*ldc + nA]) = v0;
    *reinterpret_cast<float4*>(&C[(size_t)m*ldc + nB]) = v1;
  }
}

// ---------------------------------------------------------------------------
// Fused logits GEMM + per-tile row reduction (R14-proven). XCD-swizzled.
// ---------------------------------------------------------------------------
__global__ __launch_bounds__(256)
void k_logits(const float* __restrict__ A, const float* __restrict__ Bw,
              const int* __restrict__ trg,
              float* __restrict__ Pmax, int* __restrict__ Parg,
              float* __restrict__ Psum, float* __restrict__ Ltgt)
{
  const int tid = threadIdx.x;
  const int j8   = blockIdx.x & 7;
  const int mb   = (blockIdx.x >> 3) & 15;
  const int nb   = ((blockIdx.x >> 7) << 3) + j8;
  if (nb >= NTILE) return;
  const int m0 = mb*128, n0 = nb*128;

  __shared__ alignas(16) float As[16][132];
  __shared__ alignas(16) float Bs[16][132];
  const int tx = tid & 15;
  const int ty = tid >> 4;
  float acc[8][8];
  #pragma unroll
  for (int i=0;i<8;i++)
    #pragma unroll
    for (int j=0;j<8;j++) acc[i][j]=0.f;

  for (int kt=0; kt<512; kt+=16) {
    #pragma unroll
    for (int i=tid; i<128*16; i+=256) {
      int m = i>>4, k = i&15;
      As[k][m] = A[(size_t)(m0+m)*512 + kt + k];
    }
    #pragma unroll
    for (int i=tid; i<128*16; i+=256) {
      int n = i>>4, k = i&15;
      int gn = n0+n;
      Bs[k][n] = (gn < NVOC) ? Bw[(size_t)gn*512 + kt + k] : 0.f;
    }
    __syncthreads();
    #pragma unroll
    for (int k=0;k<16;k++) {
      float4 a0 = *reinterpret_cast<const float4*>(&As[k][ty*4]);
      float4 a1 = *reinterpret_cast<const float4*>(&As[k][64+ty*4]);
      float4 b0 = *reinterpret_cast<const float4*>(&Bs[k][tx*4]);
      float4 b1 = *reinterpret_cast<const float4*>(&Bs[k][64+tx*4]);
      float av[8] = {a0.x,a0.y,a0.z,a0.w,a1.x,a1.y,a1.z,a1.w};
      float bv[8] = {b0.x,b0.y,b0.z,b0.w,b1.x,b1.y,b1.z,b1.w};
      #pragma unroll
      for (int i=0;i<8;i++)
        #pragma unroll
        for (int j=0;j<8;j++)
          acc[i][j] = fmaf(av[i], bv[j], acc[i][j]);
    }
    __syncthreads();
  }

  #pragma unroll
  for (int i=0;i<8;i++) {
    int r = m0 + ((i<4) ? ty*4+i : 64+ty*4+(i-4));   // row = step*32 + b
    int step = r >> 5, b = r & 31;
    int tgt = trg[b*TTRG + step + 1];
    int ti = tgt - 4;
    float m = -3.4e38f; int am = 0x7fffffff;
    #pragma unroll
    for (int j=0;j<8;j++) {
      int gn = n0 + ((j<4) ? tx*4+j : 64+tx*4+(j-4));
      if (gn < NVOC) {
        float x = acc[i][j];
        if (x > m || (x == m && gn < am)) { m = x; am = gn; }
      }
    }
    float s = 0.f;
    float lt = 0.f;
    #pragma unroll
    for (int j=0;j<8;j++) {
      int gn = n0 + ((j<4) ? tx*4+j : 64+tx*4+(j-4));
      if (gn < NVOC) {
        s += expf(acc[i][j] - m);
        if (gn == ti) lt = acc[i][j];
      }
    }
    #pragma unroll
    for (int d=1; d<16; d<<=1) {
      float m2 = __shfl_xor(m, d);
      int   a2 = __shfl_xor(am, d);
      float s2 = __shfl_xor(s, d);
      float l2 = __shfl_xor(lt, d);
      float M = fmaxf(m, m2);
      s = s*expf(m - M) + s2*expf(m2 - M);
      if (m2 > m || (m2 == m && a2 < am)) am = a2;
      m = M;
      lt += l2;
    }
    if (tx == 0) {
      size_t pi = (size_t)r*NTILE + nb;
      Pmax[pi] = m; Parg[pi] = am; Psum[pi] = s;
      if (ti >= n0 && ti < n0 + 128) Ltgt[r] = lt;
    }
  }
}

// ---------------------------------------------------------------------------
// Tiled GEMM (64x64, used for W1 only): C = A*B^T, tanh epilogue.
// ---------------------------------------------------------------------------
struct GArgs {
  const float* A;  int lda;
  const float* Bw; int ldb;
  const float* bias;
  float* C; int ldc;
  int N; int K; int nNb; int act;
};

template<int BM,int BN,int BK,int TM,int TN>
__global__ __launch_bounds__(256)
void k_gemm(GArgs a)
{
  const int tid = threadIdx.x;
  const int mb = blockIdx.x / a.nNb;
  const int nb = blockIdx.x % a.nNb;
  const int m0 = mb*BM, n0 = nb*BN;
  const float* A  = a.A + (size_t)m0*a.lda;
  const float* Bw = a.Bw;

  __shared__ float As[BK][BM+1];
  __shared__ float Bs[BK][BN+4];
  const int tx = tid % (BN/TN);
  const int ty = tid / (BN/TN);
  float acc[TM][TN];
  #pragma unroll
  for (int i=0;i<TM;i++)
    #pragma unroll
    for (int j=0;j<TN;j++) acc[i][j]=0.f;

  for (int kt=0; kt<a.K; kt+=BK) {
    #pragma unroll
    for (int i=tid; i<BM*BK; i+=256) {
      int m = i/BK, k = i%BK;
      As[k][m] = A[(size_t)m*a.lda + kt + k];
    }
    #pragma unroll
    for (int i=tid; i<BN*BK; i+=256) {
      int n = i/BK, k = i%BK;
      int gn = n0+n;
      Bs[k][n] = (gn < a.N) ? Bw[(size_t)gn*a.ldb + kt + k] : 0.f;
    }
    __syncthreads();
    #pragma unroll
    for (int k=0;k<BK;k++) {
      float av[TM], bv[TN];
      #pragma unroll
      for (int i=0;i<TM;i++) av[i]=As[k][ty*TM+i];
      #pragma unroll
      for (int j=0;j<TN;j++) bv[j]=Bs[k][tx*TN+j];
      #pragma unroll
      for (int i=0;i<TM;i++)
        #pragma unroll
        for (int j=0;j<TN;j++)
          acc[i][j] = fmaf(av[i], bv[j], acc[i][j]);
    }
    __syncthreads();
  }
  #pragma unroll
  for (int i=0;i<TM;i++) {
    int m = m0 + ty*TM + i;
    #pragma unroll
    for (int j=0;j<TN;j++) {
      int n = n0 + tx*TN + j;
      if (n < a.N) {
        float v = acc[i][j];
        if (a.bias) v += a.bias[n];
        if (a.act)  v = tanhf(v);
        a.C[(size_t)m*a.ldc + n] = v;
      }
    }
  }
}

// Combine per-tile partials -> nll + pred per row.
__global__ __launch_bounds__(128)
void k_combine(const float* __restrict__ Pmax, const int* __restrict__ Parg,
               const float* __restrict__ Psum, const float* __restrict__ Ltgt,
               const int* __restrict__ trg,
               float* __restrict__ nll, float* __restrict__ outp)
{
  int r = blockIdx.x;
  int step = r >> 5, b = r & 31;
  int tid = threadIdx.x;
  __shared__ float sm[128]; __shared__ int sa[128]; __shared__ float ssum[128];
  float m = -3.4e38f; int am = 0x7fffffff; float s = 0.f;
  if (tid < NTILE) {
    size_t pi = (size_t)r*NTILE + tid;
    m = Pmax[pi]; am = Parg[pi]; s = Psum[pi];
  }
  sm[tid]=m; sa[tid]=am; ssum[tid]=s; __syncthreads();
  for (int off=64; off; off>>=1) {
    if (tid < off) {
      float m2 = sm[tid+off]; int a2 = sa[tid+off]; float s2 = ssum[tid+off];
      float m1 = sm[tid];     int a1 = sa[tid];     float s1 = ssum[tid];
      float M = fmaxf(m1, m2);
      ssum[tid] = s1*expf(m1 - M) + s2*expf(m2 - M);
      if (m2 > m1 || (m2 == m1 && a2 < a1)) sa[tid] = a2;
      sm[tid] = M;
    }
    __syncthreads();
  }
  if (tid == 0) {
    int tgt = trg[b*TTRG + step + 1];
    float nl = 0.f;
    if (tgt != 0) nl = -(Ltgt[r] - sm[0] - logf(ssum[0]));
    nll[step*32 + b] = nl;
    outp[1 + b*64 + step] = (float)(sa[0] + 4);
  }
}

// Embedding gather
__global__ void k_gather(const float* __restrict__ emb, const int* __restrict__ tok,
                         float* __restrict__ outp, int Tfull)
{
  int r = blockIdx.x;
  int t = r >> 5, b = r & 31;
  int token = tok[b*Tfull + t];
  const float4* s = (const float4*)(emb + (size_t)token*512);
  float4* d = (float4*)(outp + (size_t)r*512);
  d[threadIdx.x] = s[threadIdx.x];
}

// ---------------------------------------------------------------------------
// FUSED encoder LSTM step (layer 0): full-K gates + update + scatter to x1.
// ---------------------------------------------------------------------------
__global__ __launch_bounds__(256)
void k_estep(const float* __restrict__ Whh,   // [2][2048][512]
             const float* __restrict__ xg,    // [2048][4096]
             const float* __restrict__ hin,   // [2*32][512]
             float* __restrict__ hout,        // [2*32][512]
             float* __restrict__ cst,         // [2*32][512]
             float* __restrict__ xout, int s)
{
  const int bid = blockIdx.x;
  const int dir = bid >> 7;
  const int j0  = (bid & 127) * 4;
  const int tid = threadIdx.x;
  const int kg  = tid >> 5;
  const int b   = tid & 31;
  __shared__ float4 wl4[16*128];
  __shared__ float red[4*16*33];

  {
    const float* W = Whh + (size_t)dir*2048*512;
    for (int idx = tid; idx < 16*128; idx += 256) {
      int r = idx >> 7, c = idx & 127;
      int g = r >> 2, jj = r & 3;
      wl4[idx] = ((const float4*)(W + (size_t)(g*512 + j0 + jj)*512))[c];
    }
  }
  float4 hreg[16];
  {
    const float4* H4 = (const float4*)(hin + (size_t)dir*32*512);
    #pragma unroll
    for (int j=0;j<16;j++) hreg[j] = H4[(size_t)b*128 + kg*16 + j];
  }
  __syncthreads();

  float acc[16];
  #pragma unroll
  for (int r=0;r<16;r++) {
    const float4* wr = wl4 + r*128 + kg*16;
    float a0=0.f,a1=0.f,a2=0.f,a3=0.f;
    #pragma unroll
    for (int j=0;j<16;j++) {
      float4 w = wr[j];
      a0 = fmaf(w.x, hreg[j].x, a0);
      a1 = fmaf(w.y, hreg[j].y, a1);
      a2 = fmaf(w.z, hreg[j].z, a2);
      a3 = fmaf(w.w, hreg[j].w, a3);
    }
    acc[r] = (a0+a1)+(a2+a3);
  }
  #pragma unroll
  for (int r=0;r<16;r++) acc[r] += __shfl_xor(acc[r], 32);
  const int wv = tid >> 6;
  if ((tid & 32) == 0) {
    #pragma unroll
    for (int r=0;r<16;r++) red[wv*528 + r*33 + b] = acc[r];
  }
  __syncthreads();

  if (tid < 128) {
    int jj = tid >> 5, bb = tid & 31;
    int jh = j0 + jj;
    int t  = dir ? (63 - s) : s;
    const float* x = xg + ((size_t)t*32 + bb)*4096 + dir*2048;
    float g4[4];
    #pragma unroll
    for (int g=0; g<4; g++) {
      int r = g*4 + jj;
      g4[g] = ((red[0*528 + r*33 + bb] + red[1*528 + r*33 + bb])
             + (red[2*528 + r*33 + bb] + red[3*528 + r*33 + bb]))
             + x[g*512 + jh];
    }
    size_t ci = ((size_t)dir*32 + bb)*512 + jh;
    float cn = sigm(g4[1])*cst[ci] + sigm(g4[0])*tanhf(g4[2]);
    float hn = sigm(g4[3])*tanhf(cn);
    cst[ci] = cn;
    hout[ci] = hn;
    xout[((size_t)t*32 + bb)*1024 + dir*512 + jh] = hn;   // x1
  }
}

// ---------------------------------------------------------------------------
// MERGED step v2: blocks 0-255 = encoder L1 step s; 256-511 = decoder step s.
// Decoder computes Wih·x_t in-kernel with phased register use (xreg dies
// before hreg is loaded; Whh staged fully, k-halved hreg[16]) -> VGPR ~120.
// __launch_bounds__(256,2): force 2 blocks/CU so all 512 blocks co-resident.
// ---------------------------------------------------------------------------
__global__ __launch_bounds__(256, 2)
void k_mstep(const float* __restrict__ eWhh,   // [2][2048][512]
             const float* __restrict__ exg,    // enc L1 input gates [2048][4096]
             const float* __restrict__ ehin, float* __restrict__ ehout,
             float* __restrict__ ecst,         // [2*32][512]
             float* __restrict__ encout,       // [32][64][1024]
             const float* __restrict__ dWih,   // [4096][512]
             const float* __restrict__ dWhh,   // [4096][1024]
             const float* __restrict__ db,     // [4096]
             const float* __restrict__ xemb,   // [2048][512] trg emb (t*32+b)
             const float* __restrict__ dhin,   // [32][1024]
             float* __restrict__ dcst,         // [32][1024]
             float* __restrict__ dhall_t,      // [32][1024]
             const int* __restrict__ trg, int s)
{
  const int tid = threadIdx.x;
  const int kg  = tid >> 5;      // 0..7
  const int b   = tid & 31;
  __shared__ float4 wl4[16*256];   // 64 KB (enc uses first 32 KB)
  __shared__ float red[4*16*33];

  float acc[16];

  if (blockIdx.x < 256) {
    // ---------------- encoder L1 path (identical math to k_estep) ---------
    const int dir = blockIdx.x >> 7;
    const int j0  = (blockIdx.x & 127) * 4;
    {
      const float* W = eWhh + (size_t)dir*2048*512;
      for (int idx = tid; idx < 16*128; idx += 256) {
        int r = idx >> 7, c = idx & 127;
        int g = r >> 2, jj = r & 3;
        wl4[idx] = ((const float4*)(W + (size_t)(g*512 + j0 + jj)*512))[c];
      }
    }
    float4 hreg[16];
    {
      const float4* H4 = (const float4*)(ehin + (size_t)dir*32*512);
      #pragma unroll
      for (int j=0;j<16;j++) hreg[j] = H4[(size_t)b*128 + kg*16 + j];
    }
    __syncthreads();
    #pragma unroll
    for (int r=0;r<16;r++) {
      const float4* wr = wl4 + r*128 + kg*16;
      float a0=0.f,a1=0.f,a2=0.f,a3=0.f;
      #pragma unroll
      for (int j=0;j<16;j++) {
        float4 w = wr[j];
        a0 = fmaf(w.x, hreg[j].x, a0);
        a1 = fmaf(w.y, hreg[j].y, a1);
        a2 = fmaf(w.z, hreg[j].z, a2);
        a3 = fmaf(w.w, hreg[j].w, a3);
      }
      acc[r] = (a0+a1)+(a2+a3);
    }
    #pragma unroll
    for (int r=0;r<16;r++) acc[r] += __shfl_xor(acc[r], 32);
    const int wv = tid >> 6;
    if ((tid & 32) == 0) {
      #pragma unroll
      for (int r=0;r<16;r++) red[wv*528 + r*33 + b] = acc[r];
    }
    __syncthreads();
    if (tid < 128) {
      int jj = tid >> 5, bb = tid & 31;
      int jh = j0 + jj;
      int t  = dir ? (63 - s) : s;
      const float* x = exg + ((size_t)t*32 + bb)*4096 + dir*2048;
      float g4[4];
      #pragma unroll
      for (int g=0; g<4; g++) {
        int r = g*4 + jj;
        g4[g] = ((red[0*528 + r*33 + bb] + red[1*528 + r*33 + bb])
               + (red[2*528 + r*33 + bb] + red[3*528 + r*33 + bb]))
               + x[g*512 + jh];
      }
      size_t ci = ((size_t)dir*32 + bb)*512 + jh;
      float cn = sigm(g4[1])*ecst[ci] + sigm(g4[0])*tanhf(g4[2]);
      float hn = sigm(g4[3])*tanhf(cn);
      ecst[ci] = cn;
      ehout[ci] = hn;
      encout[((size_t)bb*64 + t)*1024 + dir*512 + jh] = hn;
    }
  } else {
    // ---------------- decoder path ----------------------------------------
    const int j0 = (blockIdx.x - 256) * 4;
    // phase 1: Wih (16 rows x 512) with xreg (dies after this phase)
    for (int idx = tid; idx < 16*128; idx += 256) {
      int r = idx >> 7, c = idx & 127;
      int g = r >> 2, jj = r & 3;
      wl4[idx] = ((const float4*)(dWih + (size_t)(g*1024 + j0 + jj)*512))[c];
    }
    {
      float4 xreg[16];
      const float4* X4 = (const float4*)(xemb + (size_t)s*32*512);
      #pragma unroll
      for (int j=0;j<16;j++) xreg[j] = X4[(size_t)b*128 + kg*16 + j];
      __syncthreads();
      #pragma unroll
      for (int r=0;r<16;r++) {
        const float4* wr = wl4 + r*128 + kg*16;
        float a0=0.f,a1=0.f,a2=0.f,a3=0.f;
        #pragma unroll
        for (int j=0;j<16;j++) {
          float4 w = wr[j];
          a0 = fmaf(w.x, xreg[j].x, a0);
          a1 = fmaf(w.y, xreg[j].y, a1);
          a2 = fmaf(w.z, xreg[j].z, a2);
          a3 = fmaf(w.w, xreg[j].w, a3);
        }
        acc[r] = (a0+a1)+(a2+a3);
      }
    }
    __syncthreads();   // phase-1 LDS reads done before overwrite
    // phase 2: stage full Whh (16 rows x 1024 = 64 KB), k-halved hreg[16]
    for (int idx = tid; idx < 16*256; idx += 256) {
      int r = idx >> 8, c = idx & 255;
      int g = r >> 2, jj = r & 3;
      wl4[idx] = ((const float4*)(dWhh + (size_t)(g*1024 + j0 + jj)*1024))[c];
    }
    __syncthreads();
    #pragma unroll
    for (int kh=0; kh<2; kh++) {
      float4 hreg[16];
      const float4* H4 = (const float4*)dhin;
      #pragma unroll
      for (int j=0;j<16;j++) hreg[j] = H4[(size_t)b*256 + kg*32 + kh*16 + j];
      #pragma unroll
      for (int r=0;r<16;r++) {
        const float4* wr = wl4 + r*256 + kg*32 + kh*16;
        float a0=0.f,a1=0.f,a2=0.f,a3=0.f;
        #pragma unroll
        for (int j=0;j<16;j++) {
          float4 w = wr[j];
          a0 = fmaf(w.x, hreg[j].x, a0);
          a1 = fmaf(w.y, hreg[j].y, a1);
          a2 = fmaf(w.z, hreg[j].z, a2);
          a3 = fmaf(w.w, hreg[j].w, a3);
        }
        acc[r] += (a0+a1)+(a2+a3);
      }
    }
    #pragma unroll
    for (int r=0;r<16;r++) acc[r] += __shfl_xor(acc[r], 32);
    const int wv = tid >> 6;
    if ((tid & 32) == 0) {
      #pragma unroll
      for (int r=0;r<16;r++) red[wv*528 + r*33 + b] = acc[r];
    }
    __syncthreads();
    if (tid < 128) {
      int jj = tid >> 5, bb = tid & 31;
      int jh = j0 + jj;
      int tgt = trg[bb*TTRG + s + 1];
      bool dm = (tgt == 0);
      float g4[4];
      #pragma unroll
      for (int g=0; g<4; g++) {
        int r = g*4 + jj;
        g4[g] = ((red[0*528 + r*33 + bb] + red[1*528 + r*33 + bb])
               + (red[2*528 + r*33 + bb] + red[3*528 + r*33 + bb]))
               + db[g*1024 + jh];
      }
      size_t ci = (size_t)bb*1024 + jh;
      float cn = sigm(g4[1])*dcst[ci] + sigm(g4[0])*tanhf(g4[2]);
      float hn = sigm(g4[3])*tanhf(cn);
      dcst[ci] = cn;                   // cell NOT masked (matches reference)
      dhall_t[ci] = dm ? 0.f : hn;     // h masked
    }
  }
}

// Pack layer-0 final states into decoder initial h/c
__global__ void k_pack(const float* __restrict__ hfin, const float* __restrict__ cfin,
                       float* __restrict__ dh, float* __restrict__ dcc)
{
  int tid = blockIdx.x*256 + threadIdx.x;   // 32768
  int j = tid & 1023, b = tid >> 10;
  int dir = j >> 9, jj = j & 511;
  size_t si = ((size_t)dir*32 + b)*512 + jj;
  dh[(size_t)b*1024 + j]  = hfin[si];
  dcc[(size_t)b*1024 + j] = cfin[si];
}

// ---------------------------------------------------------------------------
// Batched attention (phase B)
// ---------------------------------------------------------------------------
__global__ __launch_bounds__(256)
void k_attn(const float* __restrict__ Hall,    // [64][32][1024]
            const float* __restrict__ encout,  // [32][64][1024]
            const int* __restrict__ src,
            float* __restrict__ hctx)          // [2048][2048]
{
  int bid = blockIdx.x;
  int t = bid >> 5, b = bid & 31;
  int tid = threadIdx.x;
  __shared__ float sh[1024];
  __shared__ float ssc[64];
  const float* h = Hall + ((size_t)t*32 + b)*1024;
  size_t row = (size_t)t*32 + b;
  #pragma unroll
  for (int r=0;r<4;r++) {
    int jh = tid + 256*r;
    float v = h[jh];
    sh[jh] = v;
    hctx[row*2048 + jh] = v;
  }
  __syncthreads();
  {
    int tq = tid >> 2, part = tid & 3;
    const float* eo = encout + ((size_t)b*64 + tq)*1024 + part*256;
    const float* hh = sh + part*256;
    float s = 0.f;
    for (int k=0;k<256;k++) s = fmaf(hh[k], eo[k], s);
    s += __shfl_xor(s, 1);
    s += __shfl_xor(s, 2);
    if (part == 0) ssc[tq] = (src[b*TSRC + tq] == 0) ? -1e9f : s;
  }
  __syncthreads();
  if (tid < 64) {
    float v = ssc[tid];
    float m = v;
    for (int d=1; d<64; d<<=1) m = fmaxf(m, __shfl_xor(m, d));
    float e = expf(v - m);
    float su = e;
    for (int d=1; d<64; d<<=1) su += __shfl_xor(su, d);
    ssc[tid] = e / su;
  }
  __syncthreads();
  #pragma unroll
  for (int r=0;r<4;r++) {
    int k = tid + 256*r;
    float a = 0.f;
    const float* eb = encout + (size_t)b*65536 + k;
    for (int tt=0;tt<64;tt++) a = fmaf(ssc[tt], eb[tt*1024], a);
    hctx[row*2048 + 1024 + k] = a;
  }
}

// Final: loss = sum(nll)/denom
__global__ __launch_bounds__(256)
void k_final(const float* __restrict__ nll, const int* __restrict__ trg,
             float* __restrict__ outp)
{
  int tid = threadIdx.x;
  __shared__ float ss[256]; __shared__ int sc[256];
  float s = 0.f; int cnt = 0;
  for (int i=tid; i<2048; i+=256) {
    s += nll[i];
    int b = i >> 6, t = (i & 63) + 1;
    cnt += (trg[b*TTRG + t] != 0);
  }
  ss[tid]=s; sc[tid]=cnt; __syncthreads();
  for (int off=128; off; off>>=1) {
    if (tid<off) { ss[tid]+=ss[tid+off]; sc[tid]+=sc[tid+off]; }
    __syncthreads();
  }
  if (tid==0) outp[0] = ss[0] / (float)sc[0];
}

// ---------------------------------------------------------------------------
static void launch_big(hipStream_t st, const float* A, int lda,
                       const float* Bw, int ldb, const float* bias,
                       float* C, int ldc, int M, int N, int K)
{
  int nNb = N/128;
  dim3 g((M/128)*nNb, 1, 1);
  k_gemm128<<<g, dim3(256), 0, st>>>(A, lda, Bw, ldb, bias, C, ldc, K, nNb);
}

static void launch_med(hipStream_t st, const float* A, int lda,
                       const float* Bw, int ldb, const float* bias,
                       float* C, int ldc, int M, int N, int K, int act)
{
  GArgs a;
  a.A=A; a.lda=lda;
  a.Bw=Bw; a.ldb=ldb;
  a.bias=bias;
  a.C=C; a.ldc=ldc;
  a.N=N; a.K=K; a.nNb=(N+63)/64; a.act=act;
  dim3 g((M/64)*a.nNb, 1, 1);
  k_gemm<64,64,16,4,4><<<g, dim3(256), 0, st>>>(a);
}

extern "C" void kernel_launch(void* const* d_in, const int* in_sizes, int n_in,
                              void* d_out, int out_size, void* d_ws, size_t ws_size,
                              hipStream_t stream)
{
  (void)in_sizes; (void)n_in; (void)out_size; (void)ws_size;
  const int*   src   = (const int*)  d_in[0];
  const int*   trg   = (const int*)  d_in[1];
  const float* semb  = (const float*)d_in[2];
  const float* temb  = (const float*)d_in[3];
  const float* e0Wih = (const float*)d_in[4];
  const float* e0Whh = (const float*)d_in[5];
  const float* e0b   = (const float*)d_in[6];
  const float* e1Wih = (const float*)d_in[7];
  const float* e1Whh = (const float*)d_in[8];
  const float* e1b   = (const float*)d_in[9];
  const float* dWih  = (const float*)d_in[10];
  const float* dWhh  = (const float*)d_in[11];
  const float* db    = (const float*)d_in[12];
  const float* W1    = (const float*)d_in[13];
  const float* W2    = (const float*)d_in[14];
  float* out = (float*)d_out;   // f32 output

  float* ws = (float*)d_ws;
  size_t o = 0;
  float* x_in   = ws + o; o += (size_t)2048*512;    // emb; later: zt
  float* xg     = ws + o; o += (size_t)2048*4096;   // xg; later: hctx + partials
  float* x1     = ws + o; o += (size_t)2048*1024;   // layer-1 input; later: Hall
  float* encout = ws + o; o += (size_t)2048*1024;
  float* hA     = ws + o; o += 2*32*512;
  float* hB     = ws + o; o += 2*32*512;
  float* cbuf   = ws + o; o += 2*32*512;
  float* dh0    = ws + o; o += 32*1024;
  float* dc     = ws + o; o += 32*1024;
  float* nll    = ws + o; o += 2048;
  float* Hall   = x1;                        // [64][32][1024]
  float* hctx   = xg;                        // [2048][2048]
  float* zt     = x_in;                      // [2048][512]
  float* Pmax   = xg + (size_t)4*1024*1024;             // [2048][125]
  int*   Parg   = (int*)(Pmax + (size_t)2048*NTILE);    // [2048][125]
  float* Psum   = Pmax + (size_t)2*2048*NTILE;          // [2048][125]
  float* Ltgt   = Pmax + (size_t)3*2048*NTILE;          // [2048]

  // ---- encoder layer 0 ----
  hipMemsetAsync(hA,   0, 2*32*512*sizeof(float), stream);
  hipMemsetAsync(cbuf, 0, 2*32*512*sizeof(float), stream);
  k_gather<<<dim3(2048), dim3(128), 0, stream>>>(semb, src, x_in, TSRC);
  launch_big(stream, x_in, 512, e0Wih, 512, e0b, xg, 4096, 2048, 4096, 512);
  for (int s=0; s<64; s++) {
    float* hin  = (s&1) ? hB : hA;
    float* hout = (s&1) ? hA : hB;
    k_estep<<<dim3(256), dim3(256), 0, stream>>>(e0Whh, xg, hin, hout, cbuf, x1, s);
  }
  k_pack<<<dim3(128), dim3(256), 0, stream>>>(hA, cbuf, dh0, dc);

  // ---- prep: enc L1 input gates (xg) + decoder trg embeddings (x_in) ----
  hipMemsetAsync(hA,   0, 2*32*512*sizeof(float), stream);
  hipMemsetAsync(cbuf, 0, 2*32*512*sizeof(float), stream);
  launch_big(stream, x1, 1024, e1Wih, 1024, e1b, xg, 4096, 2048, 4096, 1024);
  k_gather<<<dim3(2048), dim3(128), 0, stream>>>(temb, trg, x_in, TTRG);

  // ---- MERGED loop: enc L1 (blocks 0-255) + decoder (blocks 256-511) ----
  for (int s=0; s<64; s++) {
    float* ehin  = (s&1) ? hB : hA;
    float* ehout = (s&1) ? hA : hB;
    const float* dhin = (s == 0) ? dh0 : (Hall + (size_t)(s-1)*32*1024);
    k_mstep<<<dim3(512), dim3(256), 0, stream>>>(
        e1Whh, xg, ehin, ehout, cbuf, encout,
        dWih, dWhh, db, x_in, dhin, dc, Hall + (size_t)s*32*1024, trg, s);
  }

  // ---- decoder phase B: batched attention + projections + fused logits ----
  k_attn<<<dim3(2048), dim3(256), 0, stream>>>(Hall, encout, src, hctx);
  launch_med(stream, hctx, 2048, W1, 2048, nullptr, zt, 512, 2048, 512, 2048, 1);
  k_logits<<<dim3(2048), dim3(256), 0, stream>>>(zt, W2, trg, Pmax, Parg, Psum, Ltgt);
  k_combine<<<dim3(2048), dim3(128), 0, stream>>>(Pmax, Parg, Psum, Ltgt, trg, nll, out);
  k_final<<<dim3(1), dim3(256), 0, stream>>>(nll, trg, out);
}